// Round 4
// baseline (528.483 us; speedup 1.0000x reference)
//
#include <hip/hip_runtime.h>
#include <hip/hip_bf16.h>
#include <stdint.h>

// ============================================================================
// MultiAttentionWithGating — compression branch (_kc/_vc) is DEAD CODE.
// Pipeline: qkv = x@W_attn^T ; causal SDPA (16 heads, hs=64) ; out = y@W_proj^T
//
// ROUND 4: runtime dtype dispatch. The reference declares float32; the test
// label says bf16. Rounds 1-3 NaN is fully explained by reading fp32 bits as
// bf16 (mantissa halfwords -> 0.4% NaN patterns). Each GEMM probes x's even
// halfwords (genuine bf16 values vs fp32 mantissa garbage) and selects
// fp32->bf16 converting staging vs direct bf16 staging; proj epilogue writes
// d_out in the detected dtype. Internal compute: bf16 MFMA, fp32 accum.
// Attention writes y back into q_ws (race-free: each wave reads only its own
// 16 q rows, then writes the same 16 y rows); proj reads y via head-gathered
// addressing. No D2D copy. ws use: 48 MiB.
// ============================================================================

typedef __bf16 bf16x8 __attribute__((ext_vector_type(8)));
typedef float f32x4 __attribute__((ext_vector_type(4)));
typedef __hip_bfloat16 bf16;

#define B_ 4
#define T_ 2048
#define C_ 1024
#define NH_ 16
#define HS_ 64
#define NEG_BIG (-30000.0f)

// Wave-uniform dtype probe on x: even halfwords are real bf16 values (exponent
// in [117,137] w.p. ~99.7%) iff input is bf16; fp32 mantissa halfwords hit that
// range w.p. ~8%. 64 samples -> unambiguous.
__device__ __forceinline__ bool detect_fp32(const unsigned short* px) {
  const int lane = threadIdx.x & 63;
  const unsigned short u = px[2 * lane];
  const int e = (u >> 7) & 0xff;
  const bool plausible = (e >= 117) && (e <= 137);
  return __popcll(__ballot(plausible)) < 32;
}

// Load 8 consecutive elements at element-offset `elt` as 8 bf16 (16B payload).
__device__ __forceinline__ uint4 ld8(const void* base, size_t elt, bool f32) {
  if (f32) {
    const float* fp = (const float*)base + elt;
    float4 f0 = *(const float4*)(fp);
    float4 f1 = *(const float4*)(fp + 4);
    union { bf16 h[8]; uint4 u; } r;
    r.h[0] = __float2bfloat16(f0.x); r.h[1] = __float2bfloat16(f0.y);
    r.h[2] = __float2bfloat16(f0.z); r.h[3] = __float2bfloat16(f0.w);
    r.h[4] = __float2bfloat16(f1.x); r.h[5] = __float2bfloat16(f1.y);
    r.h[6] = __float2bfloat16(f1.z); r.h[7] = __float2bfloat16(f1.w);
    return r.u;
  }
  return *(const uint4*)((const bf16*)base + elt);
}

// ----------------------------------------------------------------------------
// gemm_bt: C[m,n] = sum_k A[m,k]*B[n,k]. 128x128 tile, BK=32, 4 waves 2x2.
// IN_MODE 0: A is [M,K] row-major in detected dtype (x).
// IN_MODE 1: A is y stored in q_ws head-layout [B,NH,T,HS], always bf16:
//            A[m][k] = yq[((b*NH + k/64)*T + t)*HS + k%64], b=m>>11, t=m&2047.
// OUT_MODE 0: C[M,N] in detected dtype.
// OUT_MODE 1: bf16 scatter into q/k/v ws [B,NH,T,HS] (n<1024:q, <2048:k, else v).
// ----------------------------------------------------------------------------
template <int IN_MODE, int OUT_MODE>
__global__ __launch_bounds__(256, 2) void gemm_bt(
    const void* __restrict__ A, const void* __restrict__ B, void* __restrict__ C,
    bf16* __restrict__ k_ws, bf16* __restrict__ v_ws,
    const unsigned short* __restrict__ probe, int M, int N, int K) {
  __shared__ bf16 As[128 * 32];
  __shared__ bf16 Bs[128 * 32];

  const bool f32 = detect_fp32(probe);

  const int tid = threadIdx.x;
  const int lane = tid & 63;
  const int wid = tid >> 6;
  const int quad = lane >> 4;
  const int col = lane & 15;
  const int m0 = blockIdx.y * 128;
  const int n0 = blockIdx.x * 128;
  const int wm = (wid >> 1) * 64;
  const int wn = (wid & 1) * 64;

  // staging map: row = tid/4, 8-elem chunk = tid%4; LDS elem off = tid*8
  const size_t arow = (size_t)(m0 + (tid >> 2));
  const size_t brow = (size_t)(n0 + (tid >> 2));
  const int chunk = (tid & 3) * 8;

  f32x4 acc[4][4] = {};

  for (int k0 = 0; k0 < K; k0 += 32) {
    uint4 a0, a1;
    if (IN_MODE == 0) {
      a0 = ld8(A, arow * K + chunk + k0, f32);
      a1 = ld8(A, (arow + 64) * K + chunk + k0, f32);
    } else {
      const int b = m0 >> 11;
      const int tloc = (m0 & 2047) + (tid >> 2);
      const size_t aoff = ((((size_t)b * NH_) + (k0 >> 6)) * T_ + tloc) * HS_ +
                          (k0 & 32) + chunk;
      a0 = ld8(A, aoff, false);
      a1 = ld8(A, aoff + (size_t)64 * HS_, false);
    }
    uint4 b0 = ld8(B, brow * K + chunk + k0, f32);
    uint4 b1 = ld8(B, (brow + 64) * K + chunk + k0, f32);

    __syncthreads();  // previous iteration's ds_reads complete before overwrite
    *(uint4*)(As + tid * 8) = a0;
    *(uint4*)(As + 2048 + tid * 8) = a1;
    *(uint4*)(Bs + tid * 8) = b0;
    *(uint4*)(Bs + 2048 + tid * 8) = b1;
    __syncthreads();

    bf16x8 af[4], bfr[4];
#pragma unroll
    for (int t = 0; t < 4; ++t) {
      // A-frag: A[m=lane&15][k=quad*8+j]; B-frag mirrored: B[k=quad*8+j][n=lane&15]
      af[t] = *(const bf16x8*)(As + (wm + t * 16 + col) * 32 + quad * 8);
      bfr[t] = *(const bf16x8*)(Bs + (wn + t * 16 + col) * 32 + quad * 8);
    }
#pragma unroll
    for (int tm = 0; tm < 4; ++tm)
#pragma unroll
      for (int tn = 0; tn < 4; ++tn)
        acc[tm][tn] = __builtin_amdgcn_mfma_f32_16x16x32_bf16(
            af[tm], bfr[tn], acc[tm][tn], 0, 0, 0);
  }

  // C/D layout: col = lane&15, row = quad*4 + r
  if (OUT_MODE == 0) {
#pragma unroll
    for (int tm = 0; tm < 4; ++tm) {
      const int mrow = m0 + wm + tm * 16 + quad * 4;
#pragma unroll
      for (int tn = 0; tn < 4; ++tn) {
        const int ncol = n0 + wn + tn * 16 + col;
#pragma unroll
        for (int r = 0; r < 4; ++r) {
          if (f32)
            ((float*)C)[(size_t)(mrow + r) * N + ncol] = acc[tm][tn][r];
          else
            ((bf16*)C)[(size_t)(mrow + r) * N + ncol] =
                __float2bfloat16(acc[tm][tn][r]);
        }
      }
    }
  } else {
    const int sect = n0 >> 10;  // block's n-range lies in one of q/k/v
    bf16* dst = (sect == 0) ? (bf16*)C : ((sect == 1) ? k_ws : v_ws);
#pragma unroll
    for (int tm = 0; tm < 4; ++tm) {
      const int mrow = m0 + wm + tm * 16 + quad * 4;
#pragma unroll
      for (int tn = 0; tn < 4; ++tn) {
        const int c = (n0 + wn + tn * 16 + col) & (C_ - 1);
        const int h = c >> 6, d = c & 63;
#pragma unroll
        for (int r = 0; r < 4; ++r) {
          const int t = (mrow + r) & (T_ - 1);
          const int b = (mrow + r) >> 11;
          dst[(((size_t)b * NH_ + h) * T_ + t) * HS_ + d] =
              __float2bfloat16(acc[tm][tn][r]);
        }
      }
    }
  }
}

// ----------------------------------------------------------------------------
// MFMA flash attention (causal). Block = one (b,h) x 64 q rows; 4 waves x 16
// rows. 64-key tiles, online softmax, P via per-wave LDS round-trip.
// y is written back into the q workspace (head layout) — race-free because
// each wave reads exactly its own 16 q rows (at kernel start) and later writes
// only those same 16 rows.
// ----------------------------------------------------------------------------
__global__ __launch_bounds__(256, 2) void attn(
    bf16* qy, const bf16* __restrict__ kws, const bf16* __restrict__ vws) {
  __shared__ bf16 Ks[64 * 72];     // [key][d], stride 72 (16B-aligned rows)
  __shared__ bf16 Vs[64 * 68];     // [key][d], stride 68 (breaks u16 bank alias)
  __shared__ bf16 Ps[4][16 * 72];  // per-wave P tile [16 q][64 k]

  const int tid = threadIdx.x;
  const int lane = tid & 63;
  const int w = tid >> 6;
  const int quad = lane >> 4;
  const int col = lane & 15;
  const int qb = blockIdx.x;  // 0..31
  const int bh = blockIdx.y;  // 0..63
  const size_t head_off = (size_t)bh * T_ * HS_;

  // Q A-fragments: A[m=col][k=quad*8+j] per 32-wide d-half
  const int qrow = qb * 64 + w * 16 + col;
  const bf16* qp = qy + head_off + (size_t)qrow * HS_ + quad * 8;
  bf16x8 qf0 = *(const bf16x8*)(qp);
  bf16x8 qf1 = *(const bf16x8*)(qp + 32);

  f32x4 o[4] = {};
  float m_i[4], l_i[4];
#pragma unroll
  for (int r = 0; r < 4; ++r) { m_i[r] = NEG_BIG; l_i[r] = 0.0f; }

  bf16* pw = &Ps[w][0];
  const int ntiles = qb + 1;

  for (int kt = 0; kt < ntiles; ++kt) {
    const int k0 = kt * 64;
    __syncthreads();
    for (int c = tid; c < 512; c += 256) {
      const int row = c >> 3, ch = c & 7;
      const size_t goff = head_off + (size_t)(k0 + row) * HS_ + ch * 8;
      uint4 kv = *(const uint4*)(kws + goff);
      *(uint4*)(Ks + row * 72 + ch * 8) = kv;
      uint4 vv = *(const uint4*)(vws + goff);
      *(uint2*)(Vs + row * 68 + ch * 8) = make_uint2(vv.x, vv.y);
      *(uint2*)(Vs + row * 68 + ch * 8 + 4) = make_uint2(vv.z, vv.w);
    }
    __syncthreads();

    // S = Q K^T
    f32x4 s[4];
#pragma unroll
    for (int nt = 0; nt < 4; ++nt) {
      const bf16* kp = Ks + (nt * 16 + col) * 72 + quad * 8;
      bf16x8 kf0 = *(const bf16x8*)(kp);
      bf16x8 kf1 = *(const bf16x8*)(kp + 32);
      f32x4 a = {};
      a = __builtin_amdgcn_mfma_f32_16x16x32_bf16(qf0, kf0, a, 0, 0, 0);
      a = __builtin_amdgcn_mfma_f32_16x16x32_bf16(qf1, kf1, a, 0, 0, 0);
      s[nt] = a;
    }

    // scale + causal mask + online softmax
    const int qg = qb * 64 + w * 16 + quad * 4;
    float al[4];
#pragma unroll
    for (int r = 0; r < 4; ++r) {
      float mxr = NEG_BIG;
#pragma unroll
      for (int nt = 0; nt < 4; ++nt) {
        float sv = s[nt][r] * 0.125f;
        if (k0 + nt * 16 + col > qg + r) sv = NEG_BIG;
        s[nt][r] = sv;
        mxr = fmaxf(mxr, sv);
      }
#pragma unroll
      for (int msk = 1; msk < 16; msk <<= 1)
        mxr = fmaxf(mxr, __shfl_xor(mxr, msk, 64));
      const float mn = fmaxf(m_i[r], mxr);
      al[r] = __expf(m_i[r] - mn);
      m_i[r] = mn;
      float sum = 0.0f;
#pragma unroll
      for (int nt = 0; nt < 4; ++nt) {
        float p = __expf(s[nt][r] - mn);
        bf16 pb = __float2bfloat16(p);
        sum += __bfloat162float(pb);
        pw[(quad * 4 + r) * 72 + nt * 16 + col] = pb;
      }
#pragma unroll
      for (int msk = 1; msk < 16; msk <<= 1) sum += __shfl_xor(sum, msk, 64);
      l_i[r] = l_i[r] * al[r] + sum;
    }
#pragma unroll
    for (int dt = 0; dt < 4; ++dt)
#pragma unroll
      for (int r = 0; r < 4; ++r) o[dt][r] *= al[r];

    __asm__ __volatile__("s_waitcnt lgkmcnt(0)" ::: "memory");

    // O += P V
#pragma unroll
    for (int half = 0; half < 2; ++half) {
      bf16x8 pf = *(const bf16x8*)(pw + col * 72 + half * 32 + quad * 8);
#pragma unroll
      for (int dt = 0; dt < 4; ++dt) {
        union { unsigned short u[8]; bf16x8 v; } vf;
#pragma unroll
        for (int j = 0; j < 8; ++j)
          vf.u[j] = *(const unsigned short*)(Vs + (half * 32 + quad * 8 + j) * 68 +
                                             dt * 16 + col);
        o[dt] = __builtin_amdgcn_mfma_f32_16x16x32_bf16(pf, vf.v, o[dt], 0, 0, 0);
      }
    }
  }

  // epilogue: y (head layout, overwrites this wave's own q rows)
  float inv[4];
#pragma unroll
  for (int r = 0; r < 4; ++r) inv[r] = 1.0f / l_i[r];
#pragma unroll
  for (int dt = 0; dt < 4; ++dt)
#pragma unroll
    for (int r = 0; r < 4; ++r) {
      const int q = qb * 64 + w * 16 + quad * 4 + r;
      qy[head_off + (size_t)q * HS_ + dt * 16 + col] =
          __float2bfloat16(o[dt][r] * inv[r]);
    }
}

// ----------------------------------------------------------------------------
extern "C" void kernel_launch(void* const* d_in, const int* in_sizes, int n_in,
                              void* d_out, int out_size, void* d_ws, size_t ws_size,
                              hipStream_t stream) {
  const void* x = d_in[0];       // [4,2048,1024]  fp32 or bf16 (runtime-probed)
  const void* W_attn = d_in[1];  // [3072,1024]
  const void* W_proj = d_in[2];  // [1024,1024]
  const unsigned short* probe = (const unsigned short*)d_in[0];
  // d_in[3..6]: dead code in the reference.

  const size_t qkv_elems = (size_t)B_ * NH_ * T_ * HS_;  // 8388608
  bf16* q_ws = (bf16*)d_ws;
  bf16* k_ws = q_ws + qkv_elems;
  bf16* v_ws = k_ws + qkv_elems;   // total 48 MiB

  const int M = B_ * T_;  // 8192

  // 1) qkv projection -> q/k/v ws (bf16 head layout)
  gemm_bt<0, 1><<<dim3(3 * C_ / 128, M / 128), 256, 0, stream>>>(
      x, W_attn, q_ws, k_ws, v_ws, probe, M, 3 * C_, C_);

  // 2) causal flash attention; y overwrites q_ws in head layout
  attn<<<dim3(T_ / 64, B_ * NH_), 256, 0, stream>>>(q_ws, k_ws, v_ws);

  // 3) output projection: A = y (head layout, bf16), out dtype per probe
  gemm_bt<1, 0><<<dim3(C_ / 128, M / 128), 256, 0, stream>>>(
      q_ws, W_proj, d_out, nullptr, nullptr, probe, M, C_, C_);
}